// Round 7
// baseline (463.051 us; speedup 1.0000x reference)
//
#include <hip/hip_runtime.h>

#define L_SEQ 2048
#define BATCH 16
#define DDIM  1024
#define MDIM  (L_SEQ * BATCH)   // 32768
#define NDIM  (3 * DDIM)        // 3072
#define KDIM  DDIM              // 1024
#define CH    (BATCH * DDIM)    // 16384
#define NSEG  32
#define SEGL  64                // L_SEQ / NSEG

typedef __attribute__((ext_vector_type(8))) short short8;
typedef __attribute__((ext_vector_type(4))) float f32x4;

static __device__ __forceinline__ unsigned short f2bf(float f) {
  unsigned int u = __builtin_bit_cast(unsigned int, f);
  unsigned int lsb = (u >> 16) & 1u;
  u += 0x7fffu + lsb;
  return (unsigned short)(u >> 16);
}
static __device__ __forceinline__ float bf2f(unsigned short s) {
  unsigned int u = ((unsigned int)s) << 16;
  return __builtin_bit_cast(float, u);
}

static __device__ __forceinline__ void gll16(const void* g, void* l) {
  __builtin_amdgcn_global_load_lds(
      (const __attribute__((address_space(1))) unsigned int*)g,
      (__attribute__((address_space(3))) unsigned int*)l, 16, 0, 0);
}

// ---- converters ----------------------------------------------------------

__global__ void k_convert_x(const float4* __restrict__ x, ushort4* __restrict__ xb, int n4) {
  int i = blockIdx.x * blockDim.x + threadIdx.x;
  int stride = gridDim.x * blockDim.x;
  for (; i < n4; i += stride) {
    float4 v = x[i];
    ushort4 o;
    o.x = f2bf(v.x); o.y = f2bf(v.y); o.z = f2bf(v.z); o.w = f2bf(v.w);
    xb[i] = o;
  }
}

// Wb[n][k] = bf16( W[k][colmap(n)] ): regions {xt, f, r} -> contiguous col ranges
__global__ void k_convert_w(const float* __restrict__ w, unsigned short* __restrict__ wb) {
  int gid = blockIdx.x * 256 + threadIdx.x;   // 3072*1024 total
  int k = gid & (KDIM - 1);
  int n = gid >> 10;
  int col = (n < DDIM) ? 3 * n : (n < 2 * DDIM) ? 3 * (n - DDIM) + 1 : 3 * (n - 2 * DDIM) + 2;
  wb[gid] = f2bf(w[(size_t)k * NDIM + col]);
}

// ---- GEMM: 128x128 tile, 4 waves, BK=32, dbuf 32KB LDS, 3 blocks/CU ------
// R6 post-mortem: the 256^2/1-block/CU envelope is latency-bound (2 waves/SIMD
// in lockstep; no independent wave to cover stalls). This kernel trades
// FLOP/LDS-byte (43.7 -> 32) for 3 independent blocks per CU (3 waves/SIMD):
// one block's vmcnt/barrier drain hides under the other two blocks' compute
// (m114 co-scheduling). LDS 16B-slot permutation identical to R3-R6 (0 confl).

#define MFMA1(I, J, A, B) \
  acc[I][J] = __builtin_amdgcn_mfma_f32_16x16x32_bf16(A, B, acc[I][J], 0, 0, 0);

// One BK=32 tile. T = tile index; stages tile T+1 into the other buffer.
#define TILE32(T) do {                                                        \
  const char* bufC = LDSc + ((T) & 1) * 16384;                                \
  char*       bufN = LDSc + (((T) + 1) & 1) * 16384;                          \
  const int kb = (((T) + 1) & 31) * 64;                                       \
  gll16(srcA0 + kb, bufN + dstOff);                                           \
  gll16(srcA1 + kb, bufN + 4096 + dstOff);                                    \
  gll16(srcB0 + kb, bufN + 8192 + dstOff);                                    \
  gll16(srcB1 + kb, bufN + 12288 + dstOff);                                   \
  __builtin_amdgcn_sched_barrier(0);                                          \
  a0 = *(const short8*)(bufC + aRd);                                          \
  a1 = *(const short8*)(bufC + aRd + 1024);                                   \
  a2 = *(const short8*)(bufC + aRd + 2048);                                   \
  a3 = *(const short8*)(bufC + aRd + 3072);                                   \
  b0 = *(const short8*)(bufC + 8192 + bRd);                                   \
  b1 = *(const short8*)(bufC + 8192 + bRd + 1024);                            \
  b2 = *(const short8*)(bufC + 8192 + bRd + 2048);                            \
  b3 = *(const short8*)(bufC + 8192 + bRd + 3072);                            \
  MFMA1(0, 0, a0, b0) MFMA1(0, 1, a0, b1) MFMA1(0, 2, a0, b2) MFMA1(0, 3, a0, b3) \
  MFMA1(1, 0, a1, b0) MFMA1(1, 1, a1, b1) MFMA1(1, 2, a1, b2) MFMA1(1, 3, a1, b3) \
  MFMA1(2, 0, a2, b0) MFMA1(2, 1, a2, b1) MFMA1(2, 2, a2, b2) MFMA1(2, 3, a2, b3) \
  MFMA1(3, 0, a3, b0) MFMA1(3, 1, a3, b1) MFMA1(3, 2, a3, b2) MFMA1(3, 3, a3, b3) \
  asm volatile("s_waitcnt vmcnt(0)" ::: "memory");                            \
  __builtin_amdgcn_s_barrier();                                               \
} while (0)

__global__ __launch_bounds__(256, 3) void k_gemm128(
    const unsigned short* __restrict__ xb,   // [M][K] bf16
    const unsigned short* __restrict__ wb,   // [N][K] bf16
    const float* __restrict__ bias,          // [2d]
    unsigned short* __restrict__ xtb,        // [M][d] bf16
    unsigned short* __restrict__ fbuf,       // [M][d] bf16
    unsigned short* __restrict__ rbuf) {     // [M][d] bf16
  __shared__ char LDS[32768];   // 2 bufs x { A 128x64B | B 128x64B }
  char* LDSc = LDS;

  const int tid  = threadIdx.x;
  const int lane = tid & 63;
  const int wid  = tid >> 6;
  const int wr   = wid >> 1;     // 0..1
  const int wc   = wid & 1;      // 0..1

  // XCD-aware bijective swizzle: 6144 = 8 * 768; each XCD owns 32 consecutive
  // row-panels (768 = 32 mt * 24 nt) -> A-panel reuse x24 stays in one L2.
  int bid = blockIdx.x;
  int wg = (bid & 7) * 768 + (bid >> 3);
  int mt = wg / 24;
  int nt = wg - mt * 24;
  const int rowBase = mt * 128;
  const int colBase = nt * 128;

  // ds_read bases (16B-slot permutation: phys = slot ^ ((row>>1)&3))
  const int l15 = lane & 15;
  const int sl  = lane >> 4;
  const int ra0 = wr * 64 + l15;
  const int rb0 = wc * 64 + l15;
  const int aRd = ra0 * 64 + (sl ^ ((ra0 >> 1) & 3)) * 16;
  const int bRd = rb0 * 64 + (sl ^ ((rb0 >> 1) & 3)) * 16;

  // staging source bases (inverse permutation on global source, linear LDS dest)
  const int p0i = tid, p1i = 256 + tid;
  const int r0 = p0i >> 2, r1 = p1i >> 2;
  const int s0 = (p0i & 3) ^ ((r0 >> 1) & 3);
  const int s1 = (p1i & 3) ^ ((r1 >> 1) & 3);
  const char* srcA0 = (const char*)xb + (size_t)(rowBase + r0) * 2048 + s0 * 16;
  const char* srcA1 = (const char*)xb + (size_t)(rowBase + r1) * 2048 + s1 * 16;
  const char* srcB0 = (const char*)wb + (size_t)(colBase + r0) * 2048 + s0 * 16;
  const char* srcB1 = (const char*)wb + (size_t)(colBase + r1) * 2048 + s1 * 16;
  const int dstOff = wid * 1024;   // wave-uniform base; HW adds lane*16

  f32x4 acc[4][4];
#pragma unroll
  for (int ii = 0; ii < 4; ++ii)
#pragma unroll
    for (int jj = 0; jj < 4; ++jj)
      acc[ii][jj] = (f32x4){0.f, 0.f, 0.f, 0.f};

  // prologue: stage tile 0 into buffer 0
  gll16(srcA0, LDSc + dstOff);
  gll16(srcA1, LDSc + 4096 + dstOff);
  gll16(srcB0, LDSc + 8192 + dstOff);
  gll16(srcB1, LDSc + 12288 + dstOff);
  asm volatile("s_waitcnt vmcnt(0)" ::: "memory");
  __builtin_amdgcn_s_barrier();

  short8 a0, a1, a2, a3;
  short8 b0, b1, b2, b3;

  for (int i = 0; i < 16; ++i) {
    TILE32(2 * i);
    TILE32(2 * i + 1);
  }

  // epilogue: region 0 -> x_tilde (bf16), 1 -> forget, 2 -> reset
  const int region = colBase >> 10;
#pragma unroll
  for (int m = 0; m < 4; ++m) {
    int grow = rowBase + wr * 64 + m * 16 + ((lane >> 4) << 2);
#pragma unroll
    for (int n = 0; n < 4; ++n) {
      int gcol = colBase + wc * 64 + n * 16 + (lane & 15);
      f32x4 v = acc[m][n];
      if (region == 0) {
#pragma unroll
        for (int j = 0; j < 4; ++j)
          xtb[(size_t)(grow + j) * DDIM + gcol] = f2bf(v[j]);
      } else {
        float bv = bias[gcol - DDIM];
        unsigned short* dst = (region == 1) ? fbuf : rbuf;
        int lcol = gcol - (region << 10);
#pragma unroll
        for (int j = 0; j < 4; ++j) {
          float sg = 1.0f / (1.0f + __expf(-(v[j] + bv)));
          dst[(size_t)(grow + j) * DDIM + lcol] = f2bf(sg);
        }
      }
    }
  }
}

// ---- segmented scan ------------------------------------------------------
// pass 1: per (segment, channel-pair) affine state a = prod f, b = scan from 0

__global__ __launch_bounds__(256) void k_scan1(
    const unsigned short* __restrict__ fbuf,
    const unsigned short* __restrict__ xtb,
    float4* __restrict__ AB) {
  int chp = blockIdx.x * 256 + threadIdx.x;       // 0..8191 channel pairs
  int seg = blockIdx.y;
  size_t base = (size_t)seg * SEGL * CH + chp * 2;
  const unsigned int* fp = (const unsigned int*)(fbuf + base);
  const unsigned int* xp = (const unsigned int*)(xtb + base);
  float a0 = 1.f, a1 = 1.f, b0 = 0.f, b1 = 0.f;
#pragma unroll 8
  for (int s = 0; s < SEGL; ++s) {
    unsigned int fv = fp[(size_t)s * (CH / 2)];
    unsigned int xv = xp[(size_t)s * (CH / 2)];
    float f0 = bf2f((unsigned short)fv), f1 = bf2f((unsigned short)(fv >> 16));
    float x0 = bf2f((unsigned short)xv), x1 = bf2f((unsigned short)(xv >> 16));
    b0 = (b0 - x0) * f0 + x0;  a0 *= f0;
    b1 = (b1 - x1) * f1 + x1;  a1 *= f1;
  }
  AB[(size_t)seg * (CH / 2) + chp] = (float4){a0, b0, a1, b1};
}

// pass 2: scan 32 segment states per channel; emit per-segment c_in and c_last

__global__ __launch_bounds__(256) void k_scan2(
    const float* __restrict__ c0,
    const float4* __restrict__ AB,
    float* __restrict__ Cin,
    float* __restrict__ clast) {
  int chp = blockIdx.x * 256 + threadIdx.x;       // 0..8191
  float2 cc = ((const float2*)c0)[chp];
  float ca = cc.x, cb = cc.y;
#pragma unroll
  for (int s = 0; s < NSEG; ++s) {
    ((float2*)Cin)[(size_t)s * (CH / 2) + chp] = (float2){ca, cb};
    float4 ab = AB[(size_t)s * (CH / 2) + chp];
    ca = ca * ab.x + ab.y;
    cb = cb * ab.z + ab.w;
  }
  ((float2*)clast)[chp] = (float2){ca, cb};
}

// pass 3: recompute c within segment from c_in; emit h

__global__ __launch_bounds__(256) void k_scan3(
    const float* __restrict__ x,
    const unsigned short* __restrict__ fbuf,
    const unsigned short* __restrict__ xtb,
    const unsigned short* __restrict__ rbuf,
    const float* __restrict__ Cin,
    float* __restrict__ h) {
  int chp = blockIdx.x * 256 + threadIdx.x;
  int seg = blockIdx.y;
  float2 cc = ((const float2*)Cin)[(size_t)seg * (CH / 2) + chp];
  float ca = cc.x, cb = cc.y;
  size_t base = (size_t)seg * SEGL * CH + chp * 2;
  const unsigned int* fp = (const unsigned int*)(fbuf + base);
  const unsigned int* tp = (const unsigned int*)(xtb + base);
  const unsigned int* rp = (const unsigned int*)(rbuf + base);
  const float2* xp = (const float2*)(x + base);
  float2* hp = (float2*)(h + base);
#pragma unroll 4
  for (int s = 0; s < SEGL; ++s) {
    unsigned int fv = fp[(size_t)s * (CH / 2)];
    unsigned int tv = tp[(size_t)s * (CH / 2)];
    unsigned int rv = rp[(size_t)s * (CH / 2)];
    float2 xv = xp[(size_t)s * (CH / 2)];
    float f0 = bf2f((unsigned short)fv), f1 = bf2f((unsigned short)(fv >> 16));
    float t0 = bf2f((unsigned short)tv), t1 = bf2f((unsigned short)(tv >> 16));
    float r0 = bf2f((unsigned short)rv), r1 = bf2f((unsigned short)(rv >> 16));
    ca = (ca - t0) * f0 + t0;
    cb = (cb - t1) * f1 + t1;
    float e0 = __expf(-2.f * fabsf(ca));
    float e1 = __expf(-2.f * fabsf(cb));
    float g0 = copysignf((1.f - e0) / (1.f + e0), ca);
    float g1 = copysignf((1.f - e1) / (1.f + e1), cb);
    float h0 = (g0 - xv.x) * r0 + xv.x;
    float h1 = (g1 - xv.y) * r1 + xv.y;
    hp[(size_t)s * (CH / 2)] = (float2){h0, h1};
  }
}

// ---- launch --------------------------------------------------------------

extern "C" void kernel_launch(void* const* d_in, const int* in_sizes, int n_in,
                              void* d_out, int out_size, void* d_ws, size_t ws_size,
                              hipStream_t stream) {
  const float* x    = (const float*)d_in[0];
  const float* w    = (const float*)d_in[1];
  const float* bias = (const float*)d_in[2];
  const float* c0   = (const float*)d_in[3];
  float* out = (float*)d_out;
  char* ws = (char*)d_ws;

  // ws layout (207.6 MB total):
  //   [0, 6.29MB): wb (GEMM weights)  -- after GEMM, reused as AB (4MB) + Cin (2MB)
  unsigned short* wb   = (unsigned short*)(ws);
  float4*         AB   = (float4*)(ws);
  float*          Cin  = (float*)(ws + 4194304);
  unsigned short* xtb  = (unsigned short*)(ws + 6291456);
  unsigned short* fbuf = (unsigned short*)(ws + 73400320);
  unsigned short* rbuf = (unsigned short*)(ws + 140509184);
  // xb (bf16 x, 64MB) lives in d_out's h region (dead until pass 3 rewrites it)
  unsigned short* xb = (unsigned short*)d_out;

  k_convert_x<<<2048, 256, 0, stream>>>((const float4*)x, (ushort4*)xb, MDIM * KDIM / 4);
  k_convert_w<<<(NDIM * KDIM) / 256, 256, 0, stream>>>(w, wb);

  k_gemm128<<<6144, 256, 0, stream>>>(xb, wb, bias, xtb, fbuf, rbuf);

  k_scan1<<<dim3(32, NSEG), 256, 0, stream>>>(fbuf, xtb, AB);
  k_scan2<<<32, 256, 0, stream>>>(c0, AB, Cin, out + (size_t)L_SEQ * CH);
  k_scan3<<<dim3(32, NSEG), 256, 0, stream>>>(x, fbuf, xtb, rbuf, Cin, out);
}